// Round 1
// baseline (9155.257 us; speedup 1.0000x reference)
//
#include <hip/hip_runtime.h>
#include <math.h>

#define H      16
#define DK     64
#define NSEQ   2048
#define DM     1024
#define BSZ    2

// C[M,N] = A[M,K] @ W[N,K]^T + bias[N]
// 64x64 tile, 16x16 threads, 4x4 per thread, K-chunk 16, k-major LDS tiles.
template<bool HEAD_LAYOUT>
__global__ void gemm_bias(const float* __restrict__ A, const float* __restrict__ W,
                          const float* __restrict__ bias, float* __restrict__ C,
                          int M, int N, int K) {
    __shared__ float As[16][64];   // [k][m]
    __shared__ float Ws[16][64];   // [k][n]
    const int tx = threadIdx.x, ty = threadIdx.y;
    const int tid = ty * 16 + tx;
    const int m0 = blockIdx.y * 64;
    const int n0 = blockIdx.x * 64;
    const int row = tid >> 2;          // 0..63
    const int kq  = (tid & 3) << 2;    // 0,4,8,12

    float acc[4][4] = {};

    for (int k0 = 0; k0 < K; k0 += 16) {
        float4 av = *(const float4*)(&A[(size_t)(m0 + row) * K + k0 + kq]);
        As[kq + 0][row] = av.x; As[kq + 1][row] = av.y;
        As[kq + 2][row] = av.z; As[kq + 3][row] = av.w;
        float4 wv = *(const float4*)(&W[(size_t)(n0 + row) * K + k0 + kq]);
        Ws[kq + 0][row] = wv.x; Ws[kq + 1][row] = wv.y;
        Ws[kq + 2][row] = wv.z; Ws[kq + 3][row] = wv.w;
        __syncthreads();
#pragma unroll
        for (int kk = 0; kk < 16; ++kk) {
            float4 a4 = *(const float4*)(&As[kk][ty * 4]);
            float4 w4 = *(const float4*)(&Ws[kk][tx * 4]);
            float av_[4] = {a4.x, a4.y, a4.z, a4.w};
            float wv_[4] = {w4.x, w4.y, w4.z, w4.w};
#pragma unroll
            for (int i = 0; i < 4; ++i)
#pragma unroll
                for (int j = 0; j < 4; ++j)
                    acc[i][j] += av_[i] * wv_[j];
        }
        __syncthreads();
    }

#pragma unroll
    for (int i = 0; i < 4; ++i) {
        int m = m0 + ty * 4 + i;
        float4 o;
        float* po = &o.x;
#pragma unroll
        for (int j = 0; j < 4; ++j)
            po[j] = acc[i][j] + bias[n0 + tx * 4 + j];
        if (HEAD_LAYOUT) {
            int b  = m / NSEQ, nq = m % NSEQ;
            int h  = (n0 + tx * 4) / DK;        // tile spans one head (n0 multiple of 64)
            int d0 = (n0 + tx * 4) % DK;
            *(float4*)(&C[(((size_t)(b * H + h)) * NSEQ + nq) * DK + d0]) = o;
        } else {
            *(float4*)(&C[(size_t)m * N + n0 + tx * 4]) = o;
        }
    }
}

// scores = (q_h @ k_h^T) * 0.125, masked with -inf; written raw into attn buffer.
__global__ void scores_kernel(const float* __restrict__ q, const float* __restrict__ kmat,
                              const int* __restrict__ mask, float* __restrict__ attn) {
    __shared__ float Qs[64][64];   // [d][q]
    __shared__ float Ks[64][64];   // [d][kv]
    __shared__ int Ms[64];
    const int tx = threadIdx.x, ty = threadIdx.y;
    const int tid = ty * 16 + tx;
    const int bh = blockIdx.z;
    const int b  = bh / H;
    const int q0  = blockIdx.y * 64;
    const int kv0 = blockIdx.x * 64;
    const float* qh = q    + (size_t)bh * NSEQ * DK;
    const float* kh = kmat + (size_t)bh * NSEQ * DK;
    const int row = tid >> 2;
    const int kq  = (tid & 3) << 2;

    if (tid < 64) Ms[tid] = mask[b * NSEQ + kv0 + tid];
#pragma unroll
    for (int r = 0; r < 4; ++r) {
        int c = r * 16 + kq;
        float4 a = *(const float4*)(&qh[(size_t)(q0 + row) * DK + c]);
        Qs[c + 0][row] = a.x; Qs[c + 1][row] = a.y;
        Qs[c + 2][row] = a.z; Qs[c + 3][row] = a.w;
        float4 w = *(const float4*)(&kh[(size_t)(kv0 + row) * DK + c]);
        Ks[c + 0][row] = w.x; Ks[c + 1][row] = w.y;
        Ks[c + 2][row] = w.z; Ks[c + 3][row] = w.w;
    }
    __syncthreads();

    float acc[4][4] = {};
#pragma unroll
    for (int kk = 0; kk < 64; ++kk) {
        float4 a4 = *(const float4*)(&Qs[kk][ty * 4]);
        float4 w4 = *(const float4*)(&Ks[kk][tx * 4]);
        float av_[4] = {a4.x, a4.y, a4.z, a4.w};
        float wv_[4] = {w4.x, w4.y, w4.z, w4.w};
#pragma unroll
        for (int i = 0; i < 4; ++i)
#pragma unroll
            for (int j = 0; j < 4; ++j)
                acc[i][j] += av_[i] * wv_[j];
    }

    const float scale = 0.125f;   // 1/sqrt(64)
    float* arow = attn + ((size_t)bh * NSEQ + q0) * NSEQ + kv0;
#pragma unroll
    for (int i = 0; i < 4; ++i) {
        int qr = ty * 4 + i;
        float4 o;
        float* po = &o.x;
#pragma unroll
        for (int j = 0; j < 4; ++j) {
            int c = tx * 4 + j;
            po[j] = Ms[c] ? acc[i][j] * scale : -INFINITY;
        }
        *(float4*)(&arow[(size_t)qr * NSEQ + tx * 4]) = o;
    }
}

// In-place row softmax over attn rows of length NSEQ (=2048). One block per row.
__global__ void softmax_rows(float* __restrict__ attn) {
    const size_t rowi = blockIdx.x;
    float* p = attn + rowi * NSEQ;
    const int tid = threadIdx.x;

    float4 v0 = *(const float4*)(&p[tid * 8]);
    float4 v1 = *(const float4*)(&p[tid * 8 + 4]);
    float v[8] = {v0.x, v0.y, v0.z, v0.w, v1.x, v1.y, v1.z, v1.w};

    float m = -INFINITY;
#pragma unroll
    for (int i = 0; i < 8; ++i) m = fmaxf(m, v[i]);
#pragma unroll
    for (int off = 1; off < 64; off <<= 1) m = fmaxf(m, __shfl_xor(m, off));

    __shared__ float sred[4];
    const int wave = tid >> 6, lane = tid & 63;
    if (lane == 0) sred[wave] = m;
    __syncthreads();
    m = fmaxf(fmaxf(sred[0], sred[1]), fmaxf(sred[2], sred[3]));
    __syncthreads();

    float e[8], s = 0.f;
#pragma unroll
    for (int i = 0; i < 8; ++i) { e[i] = expf(v[i] - m); s += e[i]; }
#pragma unroll
    for (int off = 1; off < 64; off <<= 1) s += __shfl_xor(s, off);
    if (lane == 0) sred[wave] = s;
    __syncthreads();
    s = (sred[0] + sred[1]) + (sred[2] + sred[3]);
    const float inv = 1.0f / s;

    float4 o0 = make_float4(e[0] * inv, e[1] * inv, e[2] * inv, e[3] * inv);
    float4 o1 = make_float4(e[4] * inv, e[5] * inv, e[6] * inv, e[7] * inv);
    *(float4*)(&p[tid * 8])     = o0;
    *(float4*)(&p[tid * 8 + 4]) = o1;
}

// ao[b][q][h*DK+d] = sum_kv attn[bh][q][kv] * v[bh][kv][d]
__global__ void pv_kernel(const float* __restrict__ attn, const float* __restrict__ v,
                          float* __restrict__ ao) {
    __shared__ float Ps[64][64];   // [kv][q]
    __shared__ float Vs[64][64];   // [kv][d]
    const int tx = threadIdx.x, ty = threadIdx.y;
    const int tid = ty * 16 + tx;
    const int bh = blockIdx.z;
    const int b = bh / H, h = bh % H;
    const int q0 = blockIdx.y * 64;
    const float* vh = v    + (size_t)bh * NSEQ * DK;
    const float* ah = attn + (size_t)bh * NSEQ * NSEQ;
    const int row = tid >> 2;
    const int kq  = (tid & 3) << 2;

    float acc[4][4] = {};

    for (int kv0 = 0; kv0 < NSEQ; kv0 += 64) {
#pragma unroll
        for (int r = 0; r < 4; ++r) {
            int c = r * 16 + kq;
            float4 p4 = *(const float4*)(&ah[(size_t)(q0 + row) * NSEQ + kv0 + c]);
            Ps[c + 0][row] = p4.x; Ps[c + 1][row] = p4.y;
            Ps[c + 2][row] = p4.z; Ps[c + 3][row] = p4.w;
            float4 v4 = *(const float4*)(&vh[(size_t)(kv0 + row) * DK + c]);
            *(float4*)(&Vs[row][c]) = v4;
        }
        __syncthreads();
#pragma unroll
        for (int kk = 0; kk < 64; ++kk) {
            float4 a4 = *(const float4*)(&Ps[kk][ty * 4]);
            float4 w4 = *(const float4*)(&Vs[kk][tx * 4]);
            float av_[4] = {a4.x, a4.y, a4.z, a4.w};
            float wv_[4] = {w4.x, w4.y, w4.z, w4.w};
#pragma unroll
            for (int i = 0; i < 4; ++i)
#pragma unroll
                for (int j = 0; j < 4; ++j)
                    acc[i][j] += av_[i] * wv_[j];
        }
        __syncthreads();
    }

#pragma unroll
    for (int i = 0; i < 4; ++i) {
        int qrow = q0 + ty * 4 + i;
        float4 o = make_float4(acc[i][0], acc[i][1], acc[i][2], acc[i][3]);
        *(float4*)(&ao[((size_t)(b * NSEQ + qrow)) * DM + h * DK + tx * 4]) = o;
    }
}

extern "C" void kernel_launch(void* const* d_in, const int* in_sizes, int n_in,
                              void* d_out, int out_size, void* d_ws, size_t ws_size,
                              hipStream_t stream) {
    const float* Q    = (const float*)d_in[0];
    const float* K    = (const float*)d_in[1];
    const float* V    = (const float*)d_in[2];
    const int*   mask = (const int*)  d_in[3];
    const float* Wq   = (const float*)d_in[4];
    const float* bq   = (const float*)d_in[5];
    const float* Wk   = (const float*)d_in[6];
    const float* bk   = (const float*)d_in[7];
    const float* Wv   = (const float*)d_in[8];
    const float* bv   = (const float*)d_in[9];
    const float* Wo   = (const float*)d_in[10];
    const float* bo   = (const float*)d_in[11];

    float* out  = (float*)d_out;                            // (B, NQ, DM)
    float* attn = out + (size_t)BSZ * NSEQ * DM;            // (B, H, NQ, NKV)

    float* q  = (float*)d_ws;                               // head-major (B,H,N,DK)
    float* k  = q  + (size_t)BSZ * NSEQ * DM;
    float* v  = k  + (size_t)BSZ * NSEQ * DM;
    float* ao = v  + (size_t)BSZ * NSEQ * DM;               // (B, N, DM)

    dim3 blk(16, 16);
    dim3 g1(DM / 64, (BSZ * NSEQ) / 64);                    // (16, 64)
    gemm_bias<true ><<<g1, blk, 0, stream>>>(Q, Wq, bq, q, BSZ * NSEQ, DM, DM);
    gemm_bias<true ><<<g1, blk, 0, stream>>>(K, Wk, bk, k, BSZ * NSEQ, DM, DM);
    gemm_bias<true ><<<g1, blk, 0, stream>>>(V, Wv, bv, v, BSZ * NSEQ, DM, DM);

    dim3 g2(NSEQ / 64, NSEQ / 64, BSZ * H);                 // (32, 32, 32)
    scores_kernel<<<g2, blk, 0, stream>>>(q, k, mask, attn);

    softmax_rows<<<dim3(BSZ * H * NSEQ), dim3(256), 0, stream>>>(attn);

    dim3 g3(1, NSEQ / 64, BSZ * H);                         // (1, 32, 32)
    pv_kernel<<<g3, blk, 0, stream>>>(attn, v, ao);

    gemm_bias<false><<<g1, blk, 0, stream>>>(ao, Wo, bo, out, BSZ * NSEQ, DM, DM);
}